// Round 1
// 401.284 us; speedup vs baseline: 1.0288x; 1.0288x over previous
//
#include <hip/hip_runtime.h>
#include <math.h>

#define NL 7

// One block per (b, i). 4 waves; wave dd owns neighbor offset
// dj in {-2,-1,+1,+2}. Each lane = one (ai,aj) of its 8x8 tile, evolving all
// 8 channels through the 7-layer conv stack. Conv halo (aj +/- 1) via wave
// shuffles — no barriers in the conv loop.
//
// Output strategy (changed): d_out is zeroed by hipMemsetAsync at peak fill
// BW (~6.5 TB/s, measured from the runtime's own fill kernels); this kernel
// writes ONLY the nonzero band |i-j|<=2, j!=i — 8 KB per block, ~8 MB total,
// instead of streaming 256 MiB of mostly-zeros.
__global__ __launch_bounds__(256) void fused_kernel(
    const float* __restrict__ pw,      // (64, 1024, 1024)
    const float* __restrict__ conv_w,  // (7, 8, 8, 1, 3)
    const float* __restrict__ conv_b,  // (7, 8)
    const float* __restrict__ prelu_a, // (7,)
    float* __restrict__ out)           // (64, 1024, 1024), pre-zeroed
{
    __shared__ float wts[NL][8][8][3];
    __shared__ float bs[NL][8];
    __shared__ float al[NL];
    __shared__ float we_s[4][8][64];   // [dd][c][ai*8+aj]
    __shared__ float rowinv[64];       // [c*8+ai]

    const int b = blockIdx.x >> 7;
    const int i = blockIdx.x & 127;
    const int t = threadIdx.x;
    const int dd = t >> 6;             // wave id = neighbor slot
    const int lane = t & 63;
    const int ai = lane >> 3, aj = lane & 7;
    const int dj = (dd < 2) ? dd - 2 : dd - 1;   // -2,-1,+1,+2
    const int j = i + dj;
    const bool valid = (j >= 0) && (j < 128);

    // stage weights
    for (int p = t; p < NL * 8 * 8 * 3; p += 256) ((float*)wts)[p] = conv_w[p];
    for (int p = t; p < NL * 8; p += 256)         ((float*)bs)[p]  = conv_b[p];
    if (t < NL) al[t] = prelu_a[t];

    // load x tile (zeros for invalid neighbor)
    float x[8], h[8];
    const float* base = pw + (((size_t)(b * 8)) << 20)
                           + (size_t)(i * 8 + ai) * 1024
                           + (size_t)((valid ? j : 0) * 8 + aj);
    #pragma unroll
    for (int c = 0; c < 8; ++c) {
        x[c] = valid ? base[((size_t)c) << 20] : 0.f;
        h[c] = x[c];
    }

    __syncthreads();   // weights visible

    // 7-layer conv(1x3, pad 1 along aj) + bias + PReLU + residual.
    // Halo via shuffles: aj+/-1 stays within the wave; the tile boundary
    // (aj==0 / aj==7) is exactly the conv zero-padding.
    for (int l = 0; l < NL; ++l) {
        float v0[8], v2[8];
        #pragma unroll
        for (int ci = 0; ci < 8; ++ci) {
            float up = __shfl_up(h[ci], 1, 64);
            float dn = __shfl_down(h[ci], 1, 64);
            v0[ci] = (aj > 0) ? up : 0.f;
            v2[ci] = (aj < 7) ? dn : 0.f;
        }
        const float a = al[l];
        float nxt[8];
        #pragma unroll
        for (int co = 0; co < 8; ++co) {
            float acc = bs[l][co];
            #pragma unroll
            for (int ci = 0; ci < 8; ++ci) {
                acc += wts[l][co][ci][0] * v0[ci]
                     + wts[l][co][ci][1] * h[ci]
                     + wts[l][co][ci][2] * v2[ci];
            }
            float y = (acc >= 0.f) ? acc : a * acc;
            nxt[co] = y + h[co];
        }
        #pragma unroll
        for (int co = 0; co < 8; ++co) h[co] = nxt[co];
    }

    // gate -> we
    #pragma unroll
    for (int c = 0; c < 8; ++c) {
        float sg = 1.f / (1.f + __expf(-h[c]));
        float s = x[c] - sg;
        s = (s > 0.f) ? s : 0.f;
        float we = (valid && ai != aj) ? expm1f(s) : 0.f;
        we_s[dd][c][lane] = we;
    }
    __syncthreads();

    // row sums (row = (c, ai)): sum over the 4 neighbor tiles x 8 aj
    if (t < 64) {
        const int c = t >> 3, aii = t & 7;
        float s = 0.f;
        #pragma unroll
        for (int d2 = 0; d2 < 4; ++d2)
            #pragma unroll
            for (int a2 = 0; a2 < 8; ++a2)
                s += we_s[d2][c][aii * 8 + a2];
        rowinv[t] = 1.f / (s + 1e-5f);
    }
    __syncthreads();

    // Band-only writes: 64 rows x 8 float4 (4 j-blocks x 2 halves) = 512
    // float4 per block = 8 KB. Two iterations of 256 threads; consecutive
    // threads cover consecutive float4s of a row -> two 64 B segments per
    // row. Out-of-range neighbors skipped (memset already zeroed them).
    #pragma unroll
    for (int it = 0; it < 2; ++it) {
        const int idx   = (it << 8) | t;     // 0..511
        const int row   = idx >> 3;          // 0..63  (c, ai)
        const int q     = idx & 7;           // which of 8 inband float4s
        const int c     = row >> 3, airow = row & 7;
        const int d2    = q >> 1;            // neighbor slot 0..3
        const int half  = (q & 1) << 2;      // 0 or 4
        const int djw   = (d2 < 2) ? d2 - 2 : d2 - 1;
        const int jw    = i + djw;
        if (jw >= 0 && jw < 128) {
            const float inv = rowinv[row];
            const float* p  = &we_s[d2][c][airow * 8 + half];
            float4 v;
            v.x = p[0] * inv; v.y = p[1] * inv;
            v.z = p[2] * inv; v.w = p[3] * inv;
            *(float4*)(out + (((size_t)(b * 8 + c)) << 20)
                           + (size_t)(i * 8 + airow) * 1024
                           + (size_t)(jw * 8 + half)) = v;
        }
    }
}

extern "C" void kernel_launch(void* const* d_in, const int* in_sizes, int n_in,
                              void* d_out, int out_size, void* d_ws, size_t ws_size,
                              hipStream_t stream) {
    const float* pw      = (const float*)d_in[0];
    const float* conv_w  = (const float*)d_in[1];
    const float* conv_b  = (const float*)d_in[2];
    const float* prelu_a = (const float*)d_in[3];
    // scalars d_in[4..6] (bsz=8, cross_range=2, agent_num=8) baked in.
    (void)d_ws; (void)ws_size;

    // Zero the output at the runtime's peak fill bandwidth; the kernel then
    // writes only the ~3% nonzero band. Async + stream-ordered, so it is
    // graph-capturable and sequenced before the kernel.
    hipMemsetAsync(d_out, 0, (size_t)out_size, stream);

    fused_kernel<<<8 * 128, 256, 0, stream>>>(pw, conv_w, conv_b, prelu_a,
                                              (float*)d_out);
}